// Round 9
// baseline (383.080 us; speedup 1.0000x reference)
//
#include <hip/hip_runtime.h>

#define DEV_INLINE __device__ __forceinline__

static constexpr int KDIM = 128;
static constexpr int BUCKET_SHIFT = 8;           // 256 nodes per bucket
static constexpr int BUCKET_NODES = 1 << BUCKET_SHIFT;
static constexpr int CAP = 6144;                 // max edges per bucket (avg ~4096)
static constexpr int MAXNB = 512;                // max buckets supported

using s16x8 = __attribute__((ext_vector_type(8))) short;   // 8 bf16 (4 VGPR)
using f32x4 = __attribute__((ext_vector_type(4))) float;   // MFMA accumulator
using f32x2 = __attribute__((ext_vector_type(2))) float;

// ---------------------------------------------------------------- helpers
DEV_INLINE float bf2f_lo(unsigned int u) {
    union { unsigned int u; float f; } c; c.u = u << 16; return c.f;
}
DEV_INLINE unsigned int f2bf(float f) {      // round-to-nearest-even
    union { float f; unsigned int u; } c; c.f = f;
    return (c.u + 0x7FFFu + ((c.u >> 16) & 1u)) >> 16;
}

DEV_INLINE void fma2bf(float w, unsigned int u, float* acc) {  // 2 bf16 in a dword
    acc[0] = fmaf(w, bf2f_lo(u), acc[0]);
    acc[1] = fmaf(w, bf2f_lo(u >> 16), acc[1]);
}

DEV_INLINE void fma4fp8(float w, unsigned int u, float* acc) {  // 4 fp8 e4m3 in a dword
    f32x2 p;
    p = __builtin_amdgcn_cvt_pk_f32_fp8((int)u, false);
    acc[0] = fmaf(w, p[0], acc[0]);
    acc[1] = fmaf(w, p[1], acc[1]);
    p = __builtin_amdgcn_cvt_pk_f32_fp8((int)u, true);
    acc[2] = fmaf(w, p[0], acc[2]);
    acc[3] = fmaf(w, p[1], acc[3]);
}

DEV_INLINE unsigned char f2fp8(float f) {
    return (unsigned char)(__builtin_amdgcn_cvt_pk_fp8_f32(f, f, 0, false) & 0xFF);
}

// ---------------------------------------------------------------- bucketed CSR build
__global__ void k_zero(int* __restrict__ bucket_cursor, int nb) {
    int i = blockIdx.x * 256 + threadIdx.x;
    if (i < nb) bucket_cursor[i] = 0;
}

template <int EPT>
__global__ __launch_bounds__(256) void k_bin(
    const int* __restrict__ src, const int* __restrict__ dst,
    int* __restrict__ bucket_cursor, unsigned int* __restrict__ rec,
    int E, int NB) {
    __shared__ int hist[MAXNB];
    __shared__ int base[MAXNB];
    const int t = threadIdx.x;
    for (int i = t; i < NB; i += 256) hist[i] = 0;
    __syncthreads();

    const int e0 = blockIdx.x * (256 * EPT);
    int d[EPT], s[EPT];
#pragma unroll
    for (int i = 0; i < EPT; ++i) {
        int e = e0 + i * 256 + t;
        d[i] = (e < E) ? dst[e] : -1;
        s[i] = (e < E) ? src[e] : 0;
    }
#pragma unroll
    for (int i = 0; i < EPT; ++i)
        if (d[i] >= 0) atomicAdd(&hist[d[i] >> BUCKET_SHIFT], 1);
    __syncthreads();

    for (int i = t; i < NB; i += 256) {
        int h = hist[i];
        base[i] = (h > 0) ? atomicAdd(&bucket_cursor[i], h) : 0;
        hist[i] = 0;   // reuse as local rank cursor
    }
    __syncthreads();

#pragma unroll
    for (int i = 0; i < EPT; ++i) {
        if (d[i] >= 0) {
            int b = d[i] >> BUCKET_SHIFT;
            int r = atomicAdd(&hist[b], 1);
            unsigned int p = (unsigned int)s[i] |
                             ((unsigned int)(d[i] & (BUCKET_NODES - 1)) << 24);
            rec[(size_t)b * CAP + base[b] + r] = p;
        }
    }
}

__global__ __launch_bounds__(256) void k_degcsr(
    const int* __restrict__ bucket_cursor, const unsigned int* __restrict__ rec,
    int* __restrict__ csr_src, int* __restrict__ row_start, int* __restrict__ row_end,
    float* __restrict__ dinv, int N) {
    __shared__ int cnt[BUCKET_NODES];
    __shared__ int rstart[BUCKET_NODES];
    __shared__ int sc[BUCKET_NODES];
    const int b = blockIdx.x;
    const int t = threadIdx.x;
    const int node0 = b << BUCKET_SHIFT;
    const int ne = bucket_cursor[b];
    cnt[t] = 0;
    __syncthreads();

    const unsigned int* r0 = rec + (size_t)b * CAP;
    for (int j = t; j < ne; j += 256) atomicAdd(&cnt[r0[j] >> 24], 1);
    __syncthreads();

    int v = cnt[t];
    sc[t] = v;
    __syncthreads();
    for (int off = 1; off < 256; off <<= 1) {
        int add = (t >= off) ? sc[t - off] : 0;
        __syncthreads();
        sc[t] += add;
        __syncthreads();
    }
    int rs = sc[t] - v;  // exclusive
    rstart[t] = rs;
    if (node0 + t < N) {
        row_start[node0 + t] = b * CAP + rs;
        row_end[node0 + t]   = b * CAP + rs + v;
        dinv[node0 + t] = rsqrtf((float)v + 1.0f);  // +1 self-loop
    }
    cnt[t] = 0;  // reuse as rank cursor
    __syncthreads();

    for (int j = t; j < ne; j += 256) {
        unsigned int p = r0[j];
        int loc = p >> 24;
        int rk = atomicAdd(&cnt[loc], 1);
        csr_src[(size_t)b * CAP + rstart[loc] + rk] = (int)(p & 0x00FFFFFFu);
    }
}

// ---------------------------------------------------------------- W pre-swizzle into MFMA B-fragment order
// Wf layout: frag f = (variant*4 + kstep)*CT + ct ; ushort offset f*512 + lane*8 + j
// value = W[k][n], k = kstep*32 + (lane>>4)*8 + j, n = ct*16 + (lane&15)
__global__ void k_wprep(const float* __restrict__ W, unsigned short* __restrict__ Wf,
                        int NOUT) {
    const int tid = blockIdx.x * 256 + threadIdx.x;
    const int CT = NOUT >> 4;
    const int total = 8 * CT * 64;
    if (tid >= total) return;
    const int lane = tid & 63;
    const int f = tid >> 6;
    const int v = f / (4 * CT);
    const int r = f - v * 4 * CT;
    const int s = r / CT;
    const int ct = r - s * CT;
    const int k0 = s * 32 + ((lane >> 4) << 3);
    const int n = (ct << 4) + (lane & 15);
    unsigned int pk[4];
#pragma unroll
    for (int jp = 0; jp < 4; ++jp) {
        unsigned int h2[2];
#pragma unroll
        for (int e = 0; e < 2; ++e) {
            int j = jp * 2 + e;
            float w = W[(size_t)(k0 + j) * NOUT + n];
            unsigned int hb = f2bf(w);
            if (v) hb = f2bf(w - bf2f_lo(hb));
            h2[e] = hb;
        }
        pk[jp] = h2[0] | (h2[1] << 16);
    }
    reinterpret_cast<uint4*>(Wf)[tid] = make_uint4(pk[0], pk[1], pk[2], pk[3]);
}

// ---------------------------------------------------------------- conv1 MFMA GEMM
// Hs1 = fp8_e4m3(dinv * x@W1), 3-term bf16 split on fp32 A.
__global__ __launch_bounds__(256, 2) void k_mgemm1(
    const float* __restrict__ A, const unsigned short* __restrict__ Wf,
    const float* __restrict__ dinv,
    unsigned char* __restrict__ Hs, int N) {
    constexpr int CT = 8;                 // 128/16
    constexpr int U4 = CT * 512;
    __shared__ uint4 WfL[U4];             // 64 KB
    for (int i = threadIdx.x; i < U4; i += 256)
        WfL[i] = reinterpret_cast<const uint4*>(Wf)[i];
    __syncthreads();

    const int lane = threadIdx.x & 63;
    const int kg = lane >> 4;
    const int lm = lane & 15;
    const int r0 = blockIdx.x * 64 + (threadIdx.x >> 6) * 16;
    const int arow = r0 + lm;

    s16x8 ah[4], al[4];
    const float4* A4 = reinterpret_cast<const float4*>(A);
#pragma unroll
    for (int s = 0; s < 4; ++s) {
        float4 p0 = make_float4(0.f, 0.f, 0.f, 0.f);
        float4 p1 = p0;
        if (arow < N) {
            p0 = A4[(size_t)arow * 32 + s * 8 + kg * 2];
            p1 = A4[(size_t)arow * 32 + s * 8 + kg * 2 + 1];
        }
        float vf[8] = {p0.x, p0.y, p0.z, p0.w, p1.x, p1.y, p1.z, p1.w};
#pragma unroll
        for (int j = 0; j < 8; ++j) {
            unsigned int hb = f2bf(vf[j]);
            ah[s][j] = (short)hb;
            al[s][j] = (short)f2bf(vf[j] - bf2f_lo(hb));
        }
    }

    float dv[4];
#pragma unroll
    for (int q = 0; q < 4; ++q) {
        int orow = r0 + kg * 4 + q;
        dv[q] = (orow < N) ? dinv[orow] : 0.f;
    }

    const unsigned short* LW = reinterpret_cast<const unsigned short*>(WfL);
#pragma unroll
    for (int ct = 0; ct < CT; ++ct) {
        f32x4 acc = {0.f, 0.f, 0.f, 0.f};
#pragma unroll
        for (int s = 0; s < 4; ++s) {
            s16x8 bh = *reinterpret_cast<const s16x8*>(LW + ((size_t)(s * CT + ct)) * 512 + lane * 8);
            s16x8 bl = *reinterpret_cast<const s16x8*>(LW + ((size_t)((4 + s) * CT + ct)) * 512 + lane * 8);
            acc = __builtin_amdgcn_mfma_f32_16x16x32_bf16(ah[s], bh, acc, 0, 0, 0);
            acc = __builtin_amdgcn_mfma_f32_16x16x32_bf16(al[s], bh, acc, 0, 0, 0);
            acc = __builtin_amdgcn_mfma_f32_16x16x32_bf16(ah[s], bl, acc, 0, 0, 0);
        }
        const int col = ct * 16 + lm;
#pragma unroll
        for (int q = 0; q < 4; ++q) {
            int orow = r0 + kg * 4 + q;
            if (orow < N)
                Hs[(size_t)orow * 128 + col] = f2fp8(dv[q] * acc[q]);
        }
    }
}

// ---------------------------------------------------------------- conv2 MFMA GEMM
// A = zp (relu'd bf16, exact) -> 2-term MFMA. Hs2 = bf16(dinv * zp@W2).
__global__ __launch_bounds__(256, 4) void k_mgemm2(
    const unsigned short* __restrict__ Z, const unsigned short* __restrict__ Wf,
    const float* __restrict__ dinv,
    unsigned short* __restrict__ Hs, int N) {
    constexpr int CT = 4;                 // 64/16
    constexpr int U4 = CT * 512;
    __shared__ uint4 WfL[U4];             // 32 KB
    for (int i = threadIdx.x; i < U4; i += 256)
        WfL[i] = reinterpret_cast<const uint4*>(Wf)[i];
    __syncthreads();

    const int lane = threadIdx.x & 63;
    const int kg = lane >> 4;
    const int lm = lane & 15;
    const int r0 = blockIdx.x * 64 + (threadIdx.x >> 6) * 16;
    const int arow = r0 + lm;

    s16x8 ah[4];
    const s16x8* Z8 = reinterpret_cast<const s16x8*>(Z);
#pragma unroll
    for (int s = 0; s < 4; ++s) {
        if (arow < N) ah[s] = Z8[(size_t)arow * 16 + s * 4 + kg];
        else          ah[s] = s16x8{0, 0, 0, 0, 0, 0, 0, 0};
    }

    float dv[4];
#pragma unroll
    for (int q = 0; q < 4; ++q) {
        int orow = r0 + kg * 4 + q;
        dv[q] = (orow < N) ? dinv[orow] : 0.f;
    }

    const unsigned short* LW = reinterpret_cast<const unsigned short*>(WfL);
#pragma unroll
    for (int ct = 0; ct < CT; ++ct) {
        f32x4 acc = {0.f, 0.f, 0.f, 0.f};
#pragma unroll
        for (int s = 0; s < 4; ++s) {
            s16x8 bh = *reinterpret_cast<const s16x8*>(LW + ((size_t)(s * CT + ct)) * 512 + lane * 8);
            s16x8 bl = *reinterpret_cast<const s16x8*>(LW + ((size_t)((4 + s) * CT + ct)) * 512 + lane * 8);
            acc = __builtin_amdgcn_mfma_f32_16x16x32_bf16(ah[s], bh, acc, 0, 0, 0);
            acc = __builtin_amdgcn_mfma_f32_16x16x32_bf16(ah[s], bl, acc, 0, 0, 0);
        }
        const int col = ct * 16 + lm;
#pragma unroll
        for (int q = 0; q < 4; ++q) {
            int orow = r0 + kg * 4 + q;
            if (orow < N)
                Hs[(size_t)orow * 64 + col] = (unsigned short)f2bf(dv[q] * acc[q]);
        }
    }
}

// ---------------------------------------------------------------- conv1 aggregate, channel-sliced
// Slice = blockIdx.y (0..3), 32 fp8 channels each -> 3.2 MB table slice (L2-resident).
// blockIdx.x iterates fastest in dispatch order, so slices run ~sequentially.
// zp[node][slice] = bf16(relu( dinv*( sum_j Hs1[src_j] + Hs1[node] ) + b1 ))
__global__ void k_gather1(const int* __restrict__ row_start, const int* __restrict__ row_end,
                          const int* __restrict__ csr_src,
                          const float* __restrict__ dinv,
                          const unsigned char* __restrict__ Hs,
                          const float* __restrict__ b1,
                          unsigned short* __restrict__ Zp, int N) {
    const int lane = threadIdx.x & 7;                 // 8 lanes/node, 4 ch each
    const int node = blockIdx.x * 32 + (threadIdx.x >> 3);
    const int slice = blockIdx.y;                     // 0..3
    if (node >= N) return;
    const int s0 = row_start[node];
    const int s1 = row_end[node];
    const float dn = dinv[node];
    const unsigned int* H = reinterpret_cast<const unsigned int*>(Hs);
    const int chunk = slice * 8 + lane;               // dword index within 32-dword row
    float acc[4] = {0.f, 0.f, 0.f, 0.f};

    int j = s0;
    for (; j + 4 <= s1; j += 4) {
        int sa = csr_src[j], sb = csr_src[j + 1], sc = csr_src[j + 2], sd = csr_src[j + 3];
        unsigned int ha = H[(size_t)sa * 32 + chunk];
        unsigned int hb = H[(size_t)sb * 32 + chunk];
        unsigned int hc = H[(size_t)sc * 32 + chunk];
        unsigned int hd = H[(size_t)sd * 32 + chunk];
        fma4fp8(dn, ha, acc);
        fma4fp8(dn, hb, acc);
        fma4fp8(dn, hc, acc);
        fma4fp8(dn, hd, acc);
    }
    for (; j < s1; ++j) {
        unsigned int h = H[(size_t)csr_src[j] * 32 + chunk];
        fma4fp8(dn, h, acc);
    }
    {   // self-loop term
        unsigned int h = H[(size_t)node * 32 + chunk];
        fma4fp8(dn, h, acc);
    }

    const float4 b = *reinterpret_cast<const float4*>(b1 + slice * 32 + lane * 4);
    float f0 = fmaxf(acc[0] + b.x, 0.f);
    float f1 = fmaxf(acc[1] + b.y, 0.f);
    float f2 = fmaxf(acc[2] + b.z, 0.f);
    float f3 = fmaxf(acc[3] + b.w, 0.f);
    uint2 o;
    o.x = f2bf(f0) | (f2bf(f1) << 16);
    o.y = f2bf(f2) | (f2bf(f3) << 16);
    *reinterpret_cast<uint2*>(Zp + (size_t)node * 128 + slice * 32 + lane * 4) = o;
}

// ---------------------------------------------------------------- conv2 aggregate, channel-sliced
// Slice = blockIdx.y (0..3), 16 bf16 channels each -> 3.2 MB table slice (L2-resident).
// out[node][slice] = dinv*( sum_j Hs2[src_j] + Hs2[node] ) + b2   (fp32 write)
__global__ void k_gather2(const int* __restrict__ row_start, const int* __restrict__ row_end,
                          const int* __restrict__ csr_src,
                          const float* __restrict__ dinv,
                          const unsigned short* __restrict__ Hs,
                          const float* __restrict__ b2,
                          float* __restrict__ Out, int N) {
    const int lane = threadIdx.x & 7;                 // 8 lanes/node, 2 ch each
    const int node = blockIdx.x * 32 + (threadIdx.x >> 3);
    const int slice = blockIdx.y;                     // 0..3
    if (node >= N) return;
    const int s0 = row_start[node];
    const int s1 = row_end[node];
    const float dn = dinv[node];
    const unsigned int* H = reinterpret_cast<const unsigned int*>(Hs);
    const int chunk = slice * 8 + lane;               // dword index within 32-dword row
    float acc[2] = {0.f, 0.f};

    int j = s0;
    for (; j + 4 <= s1; j += 4) {
        int sa = csr_src[j], sb = csr_src[j + 1], sc = csr_src[j + 2], sd = csr_src[j + 3];
        unsigned int ha = H[(size_t)sa * 32 + chunk];
        unsigned int hb = H[(size_t)sb * 32 + chunk];
        unsigned int hc = H[(size_t)sc * 32 + chunk];
        unsigned int hd = H[(size_t)sd * 32 + chunk];
        fma2bf(dn, ha, acc);
        fma2bf(dn, hb, acc);
        fma2bf(dn, hc, acc);
        fma2bf(dn, hd, acc);
    }
    for (; j < s1; ++j) {
        unsigned int h = H[(size_t)csr_src[j] * 32 + chunk];
        fma2bf(dn, h, acc);
    }
    {   // self-loop term
        unsigned int h = H[(size_t)node * 32 + chunk];
        fma2bf(dn, h, acc);
    }

    const float2 b = *reinterpret_cast<const float2*>(b2 + slice * 16 + lane * 2);
    float2 o;
    o.x = acc[0] + b.x;
    o.y = acc[1] + b.y;
    *reinterpret_cast<float2*>(Out + (size_t)node * 64 + slice * 16 + lane * 2) = o;
}

// ---------------------------------------------------------------- launch
extern "C" void kernel_launch(void* const* d_in, const int* in_sizes, int n_in,
                              void* d_out, int out_size, void* d_ws, size_t ws_size,
                              hipStream_t stream) {
    const float* x  = (const float*)d_in[0];
    const int*   ei = (const int*)d_in[1];
    const float* W1 = (const float*)d_in[2];
    const float* b1 = (const float*)d_in[3];
    const float* W2 = (const float*)d_in[4];
    const float* b2 = (const float*)d_in[5];
    float* out = (float*)d_out;

    const int N = in_sizes[0] / 128;
    const int E = in_sizes[1] / 2;
    const int* src = ei;       // edge_index[0]
    const int* dst = ei + E;   // edge_index[1]
    const int NB = (N + BUCKET_NODES - 1) >> BUCKET_SHIFT;

    char* ws = (char*)d_ws;
    size_t off = 0;
    auto alloc = [&](size_t bytes) -> char* {
        char* p = ws + off;
        off += (bytes + 255) & ~size_t(255);
        return p;
    };
    int*            bucket_cursor = (int*)alloc((size_t)MAXNB * 4);
    int*            row_start     = (int*)alloc((size_t)N * 4);
    int*            row_end       = (int*)alloc((size_t)N * 4);
    float*          dinv          = (float*)alloc((size_t)N * 4);
    unsigned int*   rec           = (unsigned int*)alloc((size_t)NB * CAP * 4);
    int*            csr_src       = (int*)alloc((size_t)NB * CAP * 4);
    unsigned char*  hs1           = (unsigned char*)alloc((size_t)N * 128);      // fp8
    unsigned short* hs2           = (unsigned short*)alloc((size_t)N * 64 * 2);  // bf16
    unsigned short* zp            = (unsigned short*)alloc((size_t)N * 128 * 2); // bf16 relu'd
    unsigned short* wf1           = (unsigned short*)alloc(128 * 128 * 2 * 2);   // 64 KB
    unsigned short* wf2           = (unsigned short*)alloc(128 * 64 * 2 * 2);    // 32 KB
    (void)ws_size; (void)n_in; (void)out_size;

    constexpr int EPT = 8;
    const int bin_blocks = (E + 256 * EPT - 1) / (256 * EPT);
    const int gblk = (N + 31) / 32;    // blocks per gather slice

    hipLaunchKernelGGL(k_zero, dim3((NB + 255) / 256), dim3(256), 0, stream,
                       bucket_cursor, NB);
    hipLaunchKernelGGL(k_wprep, dim3(16), dim3(256), 0, stream, W1, wf1, 128);
    hipLaunchKernelGGL(k_wprep, dim3(8), dim3(256), 0, stream, W2, wf2, 64);
    hipLaunchKernelGGL((k_bin<EPT>), dim3(bin_blocks), dim3(256), 0, stream,
                       src, dst, bucket_cursor, rec, E, NB);
    hipLaunchKernelGGL(k_degcsr, dim3(NB), dim3(256), 0, stream,
                       bucket_cursor, rec, csr_src, row_start, row_end, dinv, N);

    // conv1 GEMM: hs1 = fp8(dinv * x@W1)
    hipLaunchKernelGGL(k_mgemm1, dim3((N + 63) / 64), dim3(256), 0, stream,
                       x, wf1, dinv, hs1, N);

    // conv1 aggregate (4 L2-resident channel slices): zp = bf16(relu(msgs + self + b1))
    hipLaunchKernelGGL(k_gather1, dim3(gblk, 4), dim3(256), 0, stream,
                       row_start, row_end, csr_src, dinv, hs1, b1, zp, N);

    // conv2 GEMM: hs2 = bf16(dinv * zp@W2)
    hipLaunchKernelGGL(k_mgemm2, dim3((N + 63) / 64), dim3(256), 0, stream,
                       zp, wf2, dinv, hs2, N);

    // conv2 aggregate (4 L2-resident channel slices): out = msgs + self + b2
    hipLaunchKernelGGL(k_gather2, dim3(gblk, 4), dim3(256), 0, stream,
                       row_start, row_end, csr_src, dinv, hs2, b2, out, N);
}

// Round 11
// 260.891 us; speedup vs baseline: 1.4684x; 1.4684x over previous
//
#include <hip/hip_runtime.h>

#define DEV_INLINE __device__ __forceinline__

static constexpr int KDIM = 128;
static constexpr int BUCKET_SHIFT = 8;           // 256 nodes per bucket
static constexpr int BUCKET_NODES = 1 << BUCKET_SHIFT;
static constexpr int CAP = 6144;                 // max edges per bucket (avg ~4096)
static constexpr int MAXNB = 512;                // max buckets supported

using s16x8 = __attribute__((ext_vector_type(8))) short;   // 8 bf16 (4 VGPR)
using f32x4 = __attribute__((ext_vector_type(4))) float;   // MFMA accumulator
using f32x2 = __attribute__((ext_vector_type(2))) float;

// ---------------------------------------------------------------- helpers
DEV_INLINE float bf2f_lo(unsigned int u) {
    union { unsigned int u; float f; } c; c.u = u << 16; return c.f;
}
DEV_INLINE unsigned int f2bf(float f) {      // round-to-nearest-even
    union { float f; unsigned int u; } c; c.f = f;
    return (c.u + 0x7FFFu + ((c.u >> 16) & 1u)) >> 16;
}

DEV_INLINE void fma8(float w, const uint4& h, float* acc) {   // 8 bf16
    acc[0] = fmaf(w, bf2f_lo(h.x), acc[0]);
    acc[1] = fmaf(w, bf2f_lo(h.x >> 16), acc[1]);
    acc[2] = fmaf(w, bf2f_lo(h.y), acc[2]);
    acc[3] = fmaf(w, bf2f_lo(h.y >> 16), acc[3]);
    acc[4] = fmaf(w, bf2f_lo(h.z), acc[4]);
    acc[5] = fmaf(w, bf2f_lo(h.z >> 16), acc[5]);
    acc[6] = fmaf(w, bf2f_lo(h.w), acc[6]);
    acc[7] = fmaf(w, bf2f_lo(h.w >> 16), acc[7]);
}

DEV_INLINE void fma4fp8(float w, unsigned int u, float* acc) {  // 4 fp8 e4m3 in a dword
    f32x2 p;
    p = __builtin_amdgcn_cvt_pk_f32_fp8((int)u, false);
    acc[0] = fmaf(w, p[0], acc[0]);
    acc[1] = fmaf(w, p[1], acc[1]);
    p = __builtin_amdgcn_cvt_pk_f32_fp8((int)u, true);
    acc[2] = fmaf(w, p[0], acc[2]);
    acc[3] = fmaf(w, p[1], acc[3]);
}
DEV_INLINE void fma16fp8(float w, const uint4& h, float* acc) { // 16 fp8
    fma4fp8(w, h.x, acc);
    fma4fp8(w, h.y, acc + 4);
    fma4fp8(w, h.z, acc + 8);
    fma4fp8(w, h.w, acc + 12);
}

DEV_INLINE unsigned char f2fp8(float f) {
    return (unsigned char)(__builtin_amdgcn_cvt_pk_fp8_f32(f, f, 0, false) & 0xFF);
}

// ---------------------------------------------------------------- bucketed CSR build
__global__ void k_zero(int* __restrict__ bucket_cursor, int nb) {
    int i = blockIdx.x * 256 + threadIdx.x;
    if (i < nb) bucket_cursor[i] = 0;
}

template <int EPT>
__global__ __launch_bounds__(256) void k_bin(
    const int* __restrict__ src, const int* __restrict__ dst,
    int* __restrict__ bucket_cursor, unsigned int* __restrict__ rec,
    int E, int NB) {
    __shared__ int hist[MAXNB];
    __shared__ int base[MAXNB];
    const int t = threadIdx.x;
    for (int i = t; i < NB; i += 256) hist[i] = 0;
    __syncthreads();

    const int e0 = blockIdx.x * (256 * EPT);
    int d[EPT], s[EPT];
#pragma unroll
    for (int i = 0; i < EPT; ++i) {
        int e = e0 + i * 256 + t;
        d[i] = (e < E) ? dst[e] : -1;
        s[i] = (e < E) ? src[e] : 0;
    }
#pragma unroll
    for (int i = 0; i < EPT; ++i)
        if (d[i] >= 0) atomicAdd(&hist[d[i] >> BUCKET_SHIFT], 1);
    __syncthreads();

    for (int i = t; i < NB; i += 256) {
        int h = hist[i];
        base[i] = (h > 0) ? atomicAdd(&bucket_cursor[i], h) : 0;
        hist[i] = 0;   // reuse as local rank cursor
    }
    __syncthreads();

#pragma unroll
    for (int i = 0; i < EPT; ++i) {
        if (d[i] >= 0) {
            int b = d[i] >> BUCKET_SHIFT;
            int r = atomicAdd(&hist[b], 1);
            unsigned int p = (unsigned int)s[i] |
                             ((unsigned int)(d[i] & (BUCKET_NODES - 1)) << 24);
            rec[(size_t)b * CAP + base[b] + r] = p;
        }
    }
}

__global__ __launch_bounds__(256) void k_degcsr(
    const int* __restrict__ bucket_cursor, const unsigned int* __restrict__ rec,
    int* __restrict__ csr_src, int* __restrict__ row_start, int* __restrict__ row_end,
    float* __restrict__ dinv, int N) {
    __shared__ int cnt[BUCKET_NODES];
    __shared__ int rstart[BUCKET_NODES];
    __shared__ int sc[BUCKET_NODES];
    const int b = blockIdx.x;
    const int t = threadIdx.x;
    const int node0 = b << BUCKET_SHIFT;
    const int ne = bucket_cursor[b];
    cnt[t] = 0;
    __syncthreads();

    const unsigned int* r0 = rec + (size_t)b * CAP;
    for (int j = t; j < ne; j += 256) atomicAdd(&cnt[r0[j] >> 24], 1);
    __syncthreads();

    int v = cnt[t];
    sc[t] = v;
    __syncthreads();
    for (int off = 1; off < 256; off <<= 1) {
        int add = (t >= off) ? sc[t - off] : 0;
        __syncthreads();
        sc[t] += add;
        __syncthreads();
    }
    int rs = sc[t] - v;  // exclusive
    rstart[t] = rs;
    if (node0 + t < N) {
        row_start[node0 + t] = b * CAP + rs;
        row_end[node0 + t]   = b * CAP + rs + v;
        dinv[node0 + t] = rsqrtf((float)v + 1.0f);  // +1 self-loop
    }
    cnt[t] = 0;  // reuse as rank cursor
    __syncthreads();

    for (int j = t; j < ne; j += 256) {
        unsigned int p = r0[j];
        int loc = p >> 24;
        int rk = atomicAdd(&cnt[loc], 1);
        csr_src[(size_t)b * CAP + rstart[loc] + rk] = (int)(p & 0x00FFFFFFu);
    }
}

// ---------------------------------------------------------------- W pre-swizzle into MFMA B-fragment order
// Wf layout: frag f = (variant*4 + kstep)*CT + ct ; ushort offset f*512 + lane*8 + j
// value = W[k][n], k = kstep*32 + (lane>>4)*8 + j, n = ct*16 + (lane&15)
__global__ void k_wprep(const float* __restrict__ W, unsigned short* __restrict__ Wf,
                        int NOUT) {
    const int tid = blockIdx.x * 256 + threadIdx.x;
    const int CT = NOUT >> 4;
    const int total = 8 * CT * 64;
    if (tid >= total) return;
    const int lane = tid & 63;
    const int f = tid >> 6;
    const int v = f / (4 * CT);
    const int r = f - v * 4 * CT;
    const int s = r / CT;
    const int ct = r - s * CT;
    const int k0 = s * 32 + ((lane >> 4) << 3);
    const int n = (ct << 4) + (lane & 15);
    unsigned int pk[4];
#pragma unroll
    for (int jp = 0; jp < 4; ++jp) {
        unsigned int h2[2];
#pragma unroll
        for (int e = 0; e < 2; ++e) {
            int j = jp * 2 + e;
            float w = W[(size_t)(k0 + j) * NOUT + n];
            unsigned int hb = f2bf(w);
            if (v) hb = f2bf(w - bf2f_lo(hb));
            h2[e] = hb;
        }
        pk[jp] = h2[0] | (h2[1] << 16);
    }
    reinterpret_cast<uint4*>(Wf)[tid] = make_uint4(pk[0], pk[1], pk[2], pk[3]);
}

// ---------------------------------------------------------------- conv1 MFMA GEMM
// Hs1 = fp8_e4m3(dinv * x@W1), 3-term bf16 split on fp32 A.
__global__ __launch_bounds__(256, 2) void k_mgemm1(
    const float* __restrict__ A, const unsigned short* __restrict__ Wf,
    const float* __restrict__ dinv,
    unsigned char* __restrict__ Hs, int N) {
    constexpr int CT = 8;                 // 128/16
    constexpr int U4 = CT * 512;
    __shared__ uint4 WfL[U4];             // 64 KB
    for (int i = threadIdx.x; i < U4; i += 256)
        WfL[i] = reinterpret_cast<const uint4*>(Wf)[i];
    __syncthreads();

    const int lane = threadIdx.x & 63;
    const int kg = lane >> 4;
    const int lm = lane & 15;
    const int r0 = blockIdx.x * 64 + (threadIdx.x >> 6) * 16;
    const int arow = r0 + lm;

    s16x8 ah[4], al[4];
    const float4* A4 = reinterpret_cast<const float4*>(A);
#pragma unroll
    for (int s = 0; s < 4; ++s) {
        float4 p0 = make_float4(0.f, 0.f, 0.f, 0.f);
        float4 p1 = p0;
        if (arow < N) {
            p0 = A4[(size_t)arow * 32 + s * 8 + kg * 2];
            p1 = A4[(size_t)arow * 32 + s * 8 + kg * 2 + 1];
        }
        float vf[8] = {p0.x, p0.y, p0.z, p0.w, p1.x, p1.y, p1.z, p1.w};
#pragma unroll
        for (int j = 0; j < 8; ++j) {
            unsigned int hb = f2bf(vf[j]);
            ah[s][j] = (short)hb;
            al[s][j] = (short)f2bf(vf[j] - bf2f_lo(hb));
        }
    }

    float dv[4];
#pragma unroll
    for (int q = 0; q < 4; ++q) {
        int orow = r0 + kg * 4 + q;
        dv[q] = (orow < N) ? dinv[orow] : 0.f;
    }

    const unsigned short* LW = reinterpret_cast<const unsigned short*>(WfL);
#pragma unroll
    for (int ct = 0; ct < CT; ++ct) {
        f32x4 acc = {0.f, 0.f, 0.f, 0.f};
#pragma unroll
        for (int s = 0; s < 4; ++s) {
            s16x8 bh = *reinterpret_cast<const s16x8*>(LW + ((size_t)(s * CT + ct)) * 512 + lane * 8);
            s16x8 bl = *reinterpret_cast<const s16x8*>(LW + ((size_t)((4 + s) * CT + ct)) * 512 + lane * 8);
            acc = __builtin_amdgcn_mfma_f32_16x16x32_bf16(ah[s], bh, acc, 0, 0, 0);
            acc = __builtin_amdgcn_mfma_f32_16x16x32_bf16(al[s], bh, acc, 0, 0, 0);
            acc = __builtin_amdgcn_mfma_f32_16x16x32_bf16(ah[s], bl, acc, 0, 0, 0);
        }
        const int col = ct * 16 + lm;
#pragma unroll
        for (int q = 0; q < 4; ++q) {
            int orow = r0 + kg * 4 + q;
            if (orow < N)
                Hs[(size_t)orow * 128 + col] = f2fp8(dv[q] * acc[q]);
        }
    }
}

// ---------------------------------------------------------------- conv2 MFMA GEMM
// A = zp (relu'd bf16, exact) -> 2-term MFMA. Hs2 = bf16(dinv * zp@W2).
__global__ __launch_bounds__(256, 4) void k_mgemm2(
    const unsigned short* __restrict__ Z, const unsigned short* __restrict__ Wf,
    const float* __restrict__ dinv,
    unsigned short* __restrict__ Hs, int N) {
    constexpr int CT = 4;                 // 64/16
    constexpr int U4 = CT * 512;
    __shared__ uint4 WfL[U4];             // 32 KB
    for (int i = threadIdx.x; i < U4; i += 256)
        WfL[i] = reinterpret_cast<const uint4*>(Wf)[i];
    __syncthreads();

    const int lane = threadIdx.x & 63;
    const int kg = lane >> 4;
    const int lm = lane & 15;
    const int r0 = blockIdx.x * 64 + (threadIdx.x >> 6) * 16;
    const int arow = r0 + lm;

    s16x8 ah[4];
    const s16x8* Z8 = reinterpret_cast<const s16x8*>(Z);
#pragma unroll
    for (int s = 0; s < 4; ++s) {
        if (arow < N) ah[s] = Z8[(size_t)arow * 16 + s * 4 + kg];
        else          ah[s] = s16x8{0, 0, 0, 0, 0, 0, 0, 0};
    }

    float dv[4];
#pragma unroll
    for (int q = 0; q < 4; ++q) {
        int orow = r0 + kg * 4 + q;
        dv[q] = (orow < N) ? dinv[orow] : 0.f;
    }

    const unsigned short* LW = reinterpret_cast<const unsigned short*>(WfL);
#pragma unroll
    for (int ct = 0; ct < CT; ++ct) {
        f32x4 acc = {0.f, 0.f, 0.f, 0.f};
#pragma unroll
        for (int s = 0; s < 4; ++s) {
            s16x8 bh = *reinterpret_cast<const s16x8*>(LW + ((size_t)(s * CT + ct)) * 512 + lane * 8);
            s16x8 bl = *reinterpret_cast<const s16x8*>(LW + ((size_t)((4 + s) * CT + ct)) * 512 + lane * 8);
            acc = __builtin_amdgcn_mfma_f32_16x16x32_bf16(ah[s], bh, acc, 0, 0, 0);
            acc = __builtin_amdgcn_mfma_f32_16x16x32_bf16(ah[s], bl, acc, 0, 0, 0);
        }
        const int col = ct * 16 + lm;
#pragma unroll
        for (int q = 0; q < 4; ++q) {
            int orow = r0 + kg * 4 + q;
            if (orow < N)
                Hs[(size_t)orow * 64 + col] = (unsigned short)f2bf(dv[q] * acc[q]);
        }
    }
}

// ---------------------------------------------------------------- conv1 aggregate
// zp[node] = bf16(relu( dinv*( sum_j Hs1[src_j] + Hs1[node] ) + b1 ))
// Hs1 fp8 [N][128]; 8 lanes/node x uint4 (16 ch each), full-row reads.
__global__ void k_gather1(const int* __restrict__ row_start, const int* __restrict__ row_end,
                          const int* __restrict__ csr_src,
                          const float* __restrict__ dinv,
                          const unsigned char* __restrict__ Hs,
                          const float* __restrict__ b1,
                          unsigned short* __restrict__ Zp, int N) {
    const int lane = threadIdx.x & 7;
    const int node = blockIdx.x * 32 + (threadIdx.x >> 3);
    if (node >= N) return;
    const int s0 = row_start[node];
    const int s1 = row_end[node];
    const float dn = dinv[node];
    const uint4* H = reinterpret_cast<const uint4*>(Hs);
    float acc[16];
#pragma unroll
    for (int i = 0; i < 16; ++i) acc[i] = 0.f;

    int j = s0;
    for (; j + 4 <= s1; j += 4) {
        int sa = csr_src[j], sb = csr_src[j + 1], sc = csr_src[j + 2], sd = csr_src[j + 3];
        uint4 ha = H[(size_t)sa * 8 + lane];
        uint4 hb = H[(size_t)sb * 8 + lane];
        uint4 hc = H[(size_t)sc * 8 + lane];
        uint4 hd = H[(size_t)sd * 8 + lane];
        fma16fp8(dn, ha, acc);
        fma16fp8(dn, hb, acc);
        fma16fp8(dn, hc, acc);
        fma16fp8(dn, hd, acc);
    }
    for (; j < s1; ++j) {
        uint4 h = H[(size_t)csr_src[j] * 8 + lane];
        fma16fp8(dn, h, acc);
    }
    {   // self-loop term
        uint4 h = H[(size_t)node * 8 + lane];
        fma16fp8(dn, h, acc);
    }

    const float4* B4 = reinterpret_cast<const float4*>(b1 + lane * 16);
    unsigned int pk[8];
#pragma unroll
    for (int p = 0; p < 4; ++p) {
        float4 b = B4[p];
        float f0 = fmaxf(acc[p * 4 + 0] + b.x, 0.f);
        float f1 = fmaxf(acc[p * 4 + 1] + b.y, 0.f);
        float f2 = fmaxf(acc[p * 4 + 2] + b.z, 0.f);
        float f3 = fmaxf(acc[p * 4 + 3] + b.w, 0.f);
        pk[p * 2]     = f2bf(f0) | (f2bf(f1) << 16);
        pk[p * 2 + 1] = f2bf(f2) | (f2bf(f3) << 16);
    }
    uint4* O = reinterpret_cast<uint4*>(Zp + (size_t)node * 128 + lane * 16);
    O[0] = make_uint4(pk[0], pk[1], pk[2], pk[3]);
    O[1] = make_uint4(pk[4], pk[5], pk[6], pk[7]);
}

// ---------------------------------------------------------------- conv2 aggregate
// out[node] = dinv*( sum_j Hs2[src_j] + Hs2[node] ) + b2   (fp32 write)
// Hs2 bf16 [N][64]; 8 lanes/node x uint4 (8 ch each), full-row reads.
__global__ void k_gather2(const int* __restrict__ row_start, const int* __restrict__ row_end,
                          const int* __restrict__ csr_src,
                          const float* __restrict__ dinv,
                          const unsigned short* __restrict__ Hs,
                          const float* __restrict__ b2,
                          float* __restrict__ Out, int N) {
    const int lane = threadIdx.x & 7;
    const int node = blockIdx.x * 32 + (threadIdx.x >> 3);
    if (node >= N) return;
    const int s0 = row_start[node];
    const int s1 = row_end[node];
    const float dn = dinv[node];
    const uint4* H8 = reinterpret_cast<const uint4*>(Hs);
    float acc[8];
#pragma unroll
    for (int i = 0; i < 8; ++i) acc[i] = 0.f;

    int j = s0;
    for (; j + 4 <= s1; j += 4) {
        int sa = csr_src[j], sb = csr_src[j + 1], sc = csr_src[j + 2], sd = csr_src[j + 3];
        uint4 ha = H8[(size_t)sa * 8 + lane];
        uint4 hb = H8[(size_t)sb * 8 + lane];
        uint4 hc = H8[(size_t)sc * 8 + lane];
        uint4 hd = H8[(size_t)sd * 8 + lane];
        fma8(dn, ha, acc);
        fma8(dn, hb, acc);
        fma8(dn, hc, acc);
        fma8(dn, hd, acc);
    }
    for (; j < s1; ++j) {
        uint4 h = H8[(size_t)csr_src[j] * 8 + lane];
        fma8(dn, h, acc);
    }
    {   // self-loop term
        uint4 h = H8[(size_t)node * 8 + lane];
        fma8(dn, h, acc);
    }

    const float4* B4 = reinterpret_cast<const float4*>(b2 + lane * 8);
    float4 b0 = B4[0], b1v = B4[1];
    float4 o0, o1;
    o0.x = acc[0] + b0.x;  o0.y = acc[1] + b0.y;  o0.z = acc[2] + b0.z;  o0.w = acc[3] + b0.w;
    o1.x = acc[4] + b1v.x; o1.y = acc[5] + b1v.y; o1.z = acc[6] + b1v.z; o1.w = acc[7] + b1v.w;
    float4* O4 = reinterpret_cast<float4*>(Out + (size_t)node * 64 + lane * 8);
    O4[0] = o0; O4[1] = o1;
}

// ---------------------------------------------------------------- launch
extern "C" void kernel_launch(void* const* d_in, const int* in_sizes, int n_in,
                              void* d_out, int out_size, void* d_ws, size_t ws_size,
                              hipStream_t stream) {
    const float* x  = (const float*)d_in[0];
    const int*   ei = (const int*)d_in[1];
    const float* W1 = (const float*)d_in[2];
    const float* b1 = (const float*)d_in[3];
    const float* W2 = (const float*)d_in[4];
    const float* b2 = (const float*)d_in[5];
    float* out = (float*)d_out;

    const int N = in_sizes[0] / 128;
    const int E = in_sizes[1] / 2;
    const int* src = ei;       // edge_index[0]
    const int* dst = ei + E;   // edge_index[1]
    const int NB = (N + BUCKET_NODES - 1) >> BUCKET_SHIFT;

    char* ws = (char*)d_ws;
    size_t off = 0;
    auto alloc = [&](size_t bytes) -> char* {
        char* p = ws + off;
        off += (bytes + 255) & ~size_t(255);
        return p;
    };
    int*            bucket_cursor = (int*)alloc((size_t)MAXNB * 4);
    int*            row_start     = (int*)alloc((size_t)N * 4);
    int*            row_end       = (int*)alloc((size_t)N * 4);
    float*          dinv          = (float*)alloc((size_t)N * 4);
    unsigned int*   rec           = (unsigned int*)alloc((size_t)NB * CAP * 4);
    int*            csr_src       = (int*)alloc((size_t)NB * CAP * 4);
    unsigned char*  hs1           = (unsigned char*)alloc((size_t)N * 128);      // fp8
    unsigned short* hs2           = (unsigned short*)alloc((size_t)N * 64 * 2);  // bf16
    unsigned short* zp            = (unsigned short*)alloc((size_t)N * 128 * 2); // bf16 relu'd
    unsigned short* wf1           = (unsigned short*)alloc(128 * 128 * 2 * 2);   // 64 KB
    unsigned short* wf2           = (unsigned short*)alloc(128 * 64 * 2 * 2);    // 32 KB
    (void)ws_size; (void)n_in; (void)out_size;

    constexpr int EPT = 8;
    const int bin_blocks = (E + 256 * EPT - 1) / (256 * EPT);

    hipLaunchKernelGGL(k_zero, dim3((NB + 255) / 256), dim3(256), 0, stream,
                       bucket_cursor, NB);
    hipLaunchKernelGGL(k_wprep, dim3(16), dim3(256), 0, stream, W1, wf1, 128);
    hipLaunchKernelGGL(k_wprep, dim3(8), dim3(256), 0, stream, W2, wf2, 64);
    hipLaunchKernelGGL((k_bin<EPT>), dim3(bin_blocks), dim3(256), 0, stream,
                       src, dst, bucket_cursor, rec, E, NB);
    hipLaunchKernelGGL(k_degcsr, dim3(NB), dim3(256), 0, stream,
                       bucket_cursor, rec, csr_src, row_start, row_end, dinv, N);

    // conv1 GEMM: hs1 = fp8(dinv * x@W1)
    hipLaunchKernelGGL(k_mgemm1, dim3((N + 63) / 64), dim3(256), 0, stream,
                       x, wf1, dinv, hs1, N);

    // conv1 aggregate: zp = bf16(relu(msgs + self + b1))
    hipLaunchKernelGGL(k_gather1, dim3((N + 31) / 32), dim3(256), 0, stream,
                       row_start, row_end, csr_src, dinv, hs1, b1, zp, N);

    // conv2 GEMM: hs2 = bf16(dinv * zp@W2)
    hipLaunchKernelGGL(k_mgemm2, dim3((N + 63) / 64), dim3(256), 0, stream,
                       zp, wf2, dinv, hs2, N);

    // conv2 aggregate: out = msgs + self + b2
    hipLaunchKernelGGL(k_gather2, dim3((N + 31) / 32), dim3(256), 0, stream,
                       row_start, row_end, csr_src, dinv, hs2, b2, out, N);
}